// Round 1
// baseline (10192.371 us; speedup 1.0000x reference)
//
#include <hip/hip_runtime.h>
#include <math.h>

#define N_NODES 100000
#define N_EDGES 1600000
#define N_QUERY 200000
#define NODE_IN 32
#define EDGE_IN 8
#define H 64
#define LAYERS 3
#define LN_EPS 1e-5f
#define BN_EPS 1e-5f

// order-preserving float->uint encoding for atomicMax
__device__ __forceinline__ unsigned encf(float x){
    unsigned u = __float_as_uint(x);
    return (u & 0x80000000u) ? ~u : (u | 0x80000000u);
}
__device__ __forceinline__ float decf(unsigned u){
    return (u & 0x80000000u) ? __uint_as_float(u & 0x7FFFFFFFu) : __uint_as_float(~u);
}
__device__ __forceinline__ float gelu_f(float x){
    return 0.5f * x * (1.0f + erff(x * 0.70710678118654752440f));
}

__global__ __launch_bounds__(256) void k_init(float* __restrict__ sum, unsigned* __restrict__ mx){
    int i = blockIdx.x * 256 + threadIdx.x;
    const int total = N_NODES * H / 4;
    if (i < total){
        ((float4*)sum)[i] = make_float4(0.f, 0.f, 0.f, 0.f);
        ((uint4*)mx)[i] = make_uint4(0x007FFFFFu, 0x007FFFFFu, 0x007FFFFFu, 0x007FFFFFu); // enc(-inf)
    }
}

__global__ __launch_bounds__(256) void k_zero_deg(float* __restrict__ deg){
    int i = blockIdx.x * 256 + threadIdx.x;
    if (i < N_NODES) deg[i] = 0.f;
}

__global__ __launch_bounds__(256) void k_deg(const int* __restrict__ ei, float* __restrict__ deg){
    int i = blockIdx.x * 256 + threadIdx.x;
    if (i < N_EDGES) atomicAdd(&deg[ei[N_EDGES + i]], 1.0f);
}

// h = x @ Wenc + benc   [N,32]@[32,64]
__global__ __launch_bounds__(256) void k_enc(const float* __restrict__ x, const float* __restrict__ Wenc,
                                             const float* __restrict__ benc, float* __restrict__ h){
    __shared__ __align__(16) float sW[NODE_IN * H];
    __shared__ float sx[4][NODE_IN];
    int tid = threadIdx.x;
    int lane = tid & 63;
    int w = tid >> 6;
    int n = blockIdx.x * 4 + w;
    for (int i = tid; i < NODE_IN * H; i += 256) sW[i] = Wenc[i];
    if (n < N_NODES && lane < NODE_IN) sx[w][lane] = x[n * NODE_IN + lane];
    __syncthreads();
    if (n < N_NODES){
        float acc = benc[lane];
        #pragma unroll
        for (int k = 0; k < NODE_IN; ++k)
            acc = fmaf(sx[w][k], sW[k * H + lane], acc);
        h[n * H + lane] = acc;
    }
}

// scatter: for each edge e, sum[dst] += h[src], max[dst] = max(.., h[src]); 16 threads/edge (float4 each)
__global__ __launch_bounds__(256) void k_scatter(const int* __restrict__ ei, const float* __restrict__ h,
                                                 float* __restrict__ sum, unsigned* __restrict__ mx){
    int t = blockIdx.x * 256 + threadIdx.x;
    const int total = N_EDGES * 16;
    if (t >= total) return;
    int e = t >> 4;
    int q = t & 15;
    int s = ei[e];
    int d = ei[N_EDGES + e];
    const float4 v = *(const float4*)(h + s * H + q * 4);
    float* sp = sum + d * H + q * 4;
    unsigned* mp = mx + d * H + q * 4;
    atomicAdd(sp + 0, v.x); atomicAdd(sp + 1, v.y); atomicAdd(sp + 2, v.z); atomicAdd(sp + 3, v.w);
    atomicMax(mp + 0, encf(v.x)); atomicMax(mp + 1, encf(v.y));
    atomicMax(mp + 2, encf(v.z)); atomicMax(mp + 3, encf(v.w));
}

// combine: h_out = gelu(LN(concat(mean,max) @ Wl + bl + h @ Wr)) + h ; one wave per node row
#define CB_WAVES 8
__global__ __launch_bounds__(512) void k_combine(const float* __restrict__ h, const float* __restrict__ sum,
    const unsigned* __restrict__ mx, const float* __restrict__ deg,
    const float* __restrict__ Wl, const float* __restrict__ bl, const float* __restrict__ Wr,
    const float* __restrict__ lng, const float* __restrict__ lnb,
    float* __restrict__ hout)
{
    __shared__ __align__(16) float sWl[H * 132];           // [f][k] transposed, stride 132 (odd f4-stride)
    __shared__ __align__(16) float sWr[H * 68];            // [f][k] transposed, stride 68
    __shared__ __align__(16) float sAggr[CB_WAVES][128];
    __shared__ __align__(16) float sH[CB_WAVES][64];
    int tid = threadIdx.x;
    for (int i = tid; i < 128 * H; i += 512){ int k = i >> 6, f = i & 63; sWl[f * 132 + k] = Wl[i]; }
    for (int i = tid; i < 64 * H;  i += 512){ int k = i >> 6, f = i & 63; sWr[f * 68 + k] = Wr[i]; }
    __syncthreads();
    int lane = tid & 63;
    int wv = tid >> 6;
    float blf = bl[lane], gf = lng[lane], bf = lnb[lane];
    int nw = gridDim.x * CB_WAVES;
    for (int n = blockIdx.x * CB_WAVES + wv; n < N_NODES; n += nw){
        float dg = deg[n];
        float sm = sum[n * H + lane];
        unsigned mu = mx[n * H + lane];
        float hv = h[n * H + lane];
        float mean = sm / fmaxf(dg, 1.0f);
        float mxv = (dg > 0.f) ? decf(mu) : 0.f;
        sAggr[wv][lane] = mean;
        sAggr[wv][64 + lane] = mxv;
        sH[wv][lane] = hv;
        asm volatile("s_waitcnt lgkmcnt(0)" ::: "memory");
        float acc = blf;
        const float4* aw = (const float4*)sAggr[wv];
        const float4* wl = (const float4*)(sWl + lane * 132);
        #pragma unroll
        for (int k4 = 0; k4 < 32; ++k4){
            float4 a = aw[k4]; float4 w = wl[k4];
            acc += a.x * w.x + a.y * w.y + a.z * w.z + a.w * w.w;
        }
        const float4* hw = (const float4*)sH[wv];
        const float4* wr = (const float4*)(sWr + lane * 68);
        #pragma unroll
        for (int k4 = 0; k4 < 16; ++k4){
            float4 a = hw[k4]; float4 w = wr[k4];
            acc += a.x * w.x + a.y * w.y + a.z * w.z + a.w * w.w;
        }
        float s1 = acc, s2 = acc * acc;
        #pragma unroll
        for (int off = 32; off; off >>= 1){
            s1 += __shfl_xor(s1, off, 64);
            s2 += __shfl_xor(s2, off, 64);
        }
        float mu_ = s1 * (1.f / 64.f);
        float var_ = s2 * (1.f / 64.f) - mu_ * mu_;
        float yv = (acc - mu_) * rsqrtf(var_ + LN_EPS) * gf + bf;
        hout[n * H + lane] = gelu_f(yv) + hv;
    }
}

// fused edge MLP: one wave per query row
#define EM_WAVES 16
__global__ __launch_bounds__(1024) void k_mlp(const float* __restrict__ h,
    const int* __restrict__ qe, const float* __restrict__ ea,
    const float* __restrict__ W1, const float* __restrict__ b1,
    const float* __restrict__ bng, const float* __restrict__ bnb,
    const float* __restrict__ bnm, const float* __restrict__ bnv,
    const float* __restrict__ W2, const float* __restrict__ b2,
    const float* __restrict__ W3, const float* __restrict__ b3,
    float* __restrict__ out)
{
    __shared__ __align__(16) float sW1[128 * 140];   // [j][k] transposed, stride 140, k<136
    __shared__ __align__(16) float sW2[64 * 132];    // [f][k] transposed, stride 132, k<128
    __shared__ __align__(16) float sZ[EM_WAVES][136];
    __shared__ __align__(16) float sZ1[EM_WAVES][128];
    int tid = threadIdx.x;
    for (int i = tid; i < 136 * 128; i += 1024){ int k = i >> 7, j = i & 127; sW1[j * 140 + k] = W1[i]; }
    for (int i = tid; i < 128 * 64; i += 1024){ int k = i >> 6, f = i & 63; sW2[f * 132 + k] = W2[i]; }
    __syncthreads();
    int lane = tid & 63, wv = tid >> 6;
    int j1 = lane + 64;
    float b10 = b1[lane], b11 = b1[j1];
    float sc0 = bng[lane] * rsqrtf(bnv[lane] + BN_EPS);
    float sh0 = bnb[lane] - bnm[lane] * sc0;
    float sc1 = bng[j1] * rsqrtf(bnv[j1] + BN_EPS);
    float sh1 = bnb[j1] - bnm[j1] * sc1;
    float b2f = b2[lane], w3f = W3[lane], b3v = b3[0];
    int nw = gridDim.x * EM_WAVES;
    for (int q = blockIdx.x * EM_WAVES + wv; q < N_QUERY; q += nw){
        int s = qe[q], t = qe[N_QUERY + q];
        sZ[wv][lane] = h[s * H + lane];
        sZ[wv][64 + lane] = h[t * H + lane];
        if (lane < EDGE_IN) sZ[wv][128 + lane] = ea[q * EDGE_IN + lane];
        asm volatile("s_waitcnt lgkmcnt(0)" ::: "memory");
        float a0 = b10, a1 = b11;
        const float4* zz = (const float4*)sZ[wv];
        const float4* w1a = (const float4*)(sW1 + lane * 140);
        const float4* w1b = (const float4*)(sW1 + j1 * 140);
        #pragma unroll
        for (int k4 = 0; k4 < 34; ++k4){
            float4 z = zz[k4];
            float4 wa = w1a[k4], wb = w1b[k4];
            a0 += z.x * wa.x + z.y * wa.y + z.z * wa.z + z.w * wa.w;
            a1 += z.x * wb.x + z.y * wb.y + z.z * wb.z + z.w * wb.w;
        }
        a0 = gelu_f(a0 * sc0 + sh0);
        a1 = gelu_f(a1 * sc1 + sh1);
        sZ1[wv][lane] = a0; sZ1[wv][j1] = a1;
        asm volatile("s_waitcnt lgkmcnt(0)" ::: "memory");
        float a2 = b2f;
        const float4* z1 = (const float4*)sZ1[wv];
        const float4* w2 = (const float4*)(sW2 + lane * 132);
        #pragma unroll
        for (int k4 = 0; k4 < 32; ++k4){
            float4 z = z1[k4]; float4 w = w2[k4];
            a2 += z.x * w.x + z.y * w.y + z.z * w.z + z.w * w.w;
        }
        a2 = gelu_f(a2);
        float pv = a2 * w3f;
        #pragma unroll
        for (int off = 32; off; off >>= 1) pv += __shfl_xor(pv, off, 64);
        if (lane == 0) out[q] = pv + b3v;
    }
}

extern "C" void kernel_launch(void* const* d_in, const int* in_sizes, int n_in,
                              void* d_out, int out_size, void* d_ws, size_t ws_size,
                              hipStream_t stream) {
    const float* x    = (const float*)d_in[0];
    const int*   ei   = (const int*)d_in[1];
    const float* ea   = (const float*)d_in[2];
    const int*   qe   = (const int*)d_in[3];
    const float* Wenc = (const float*)d_in[4];
    const float* benc = (const float*)d_in[5];
    const float* Wl   = (const float*)d_in[6];
    const float* bl   = (const float*)d_in[7];
    const float* Wr   = (const float*)d_in[8];
    const float* lng  = (const float*)d_in[9];
    const float* lnb  = (const float*)d_in[10];
    const float* W1   = (const float*)d_in[11];
    const float* b1   = (const float*)d_in[12];
    const float* bng  = (const float*)d_in[13];
    const float* bnb  = (const float*)d_in[14];
    const float* bnm  = (const float*)d_in[15];
    const float* bnv  = (const float*)d_in[16];
    const float* W2   = (const float*)d_in[17];
    const float* b2   = (const float*)d_in[18];
    const float* W3   = (const float*)d_in[19];
    const float* b3   = (const float*)d_in[20];
    float* out = (float*)d_out;

    char* ws = (char*)d_ws;
    const size_t NH = (size_t)N_NODES * H;
    float*    hA  = (float*)ws;    ws += NH * 4;
    float*    hB  = (float*)ws;    ws += NH * 4;
    float*    sum = (float*)ws;    ws += NH * 4;
    unsigned* mx  = (unsigned*)ws; ws += NH * 4;
    float*    deg = (float*)ws;    ws += (size_t)N_NODES * 4;

    k_zero_deg<<<(N_NODES + 255) / 256, 256, 0, stream>>>(deg);
    k_deg<<<(N_EDGES + 255) / 256, 256, 0, stream>>>(ei, deg);
    k_enc<<<(N_NODES + 3) / 4, 256, 0, stream>>>(x, Wenc, benc, hA);

    float* hc = hA; float* hn = hB;
    for (int l = 0; l < LAYERS; ++l){
        k_init<<<(N_NODES * H / 4 + 255) / 256, 256, 0, stream>>>(sum, mx);
        int sblocks = (N_EDGES * 16 + 255) / 256;
        k_scatter<<<sblocks, 256, 0, stream>>>(ei, hc, sum, mx);
        k_combine<<<512, 512, 0, stream>>>(hc, sum, mx, deg,
            Wl + (size_t)l * 2 * H * H, bl + l * H, Wr + (size_t)l * H * H,
            lng + l * H, lnb + l * H, hn);
        float* tmp = hc; hc = hn; hn = tmp;
    }
    k_mlp<<<256, 1024, 0, stream>>>(hc, qe, ea, W1, b1, bng, bnb, bnm, bnv, W2, b2, W3, b3, out);
}

// Round 2
// 7516.859 us; speedup vs baseline: 1.3559x; 1.3559x over previous
//
#include <hip/hip_runtime.h>
#include <math.h>

#define N_NODES 100000
#define N_EDGES 1600000
#define N_QUERY 200000
#define NODE_IN 32
#define EDGE_IN 8
#define H 64
#define LAYERS 3
#define LN_EPS 1e-5f
#define BN_EPS 1e-5f
#define NBLK 391   // ceil(N_NODES/256)

__device__ __forceinline__ float gelu_f(float x){
    return 0.5f * x * (1.0f + erff(x * 0.70710678118654752440f));
}

// ---------------- CSR build ----------------
__global__ __launch_bounds__(256) void k_zero_cnt(int* __restrict__ c){
    int i = blockIdx.x * 256 + threadIdx.x;
    if (i < N_NODES) c[i] = 0;
}
__global__ __launch_bounds__(256) void k_count(const int* __restrict__ ei, int* __restrict__ c){
    int i = blockIdx.x * 256 + threadIdx.x;
    if (i < N_EDGES) atomicAdd(&c[ei[N_EDGES + i]], 1);
}
__global__ __launch_bounds__(256) void k_scanA(const int* __restrict__ cnt, int* __restrict__ bsum){
    int i = blockIdx.x * 256 + threadIdx.x;
    int v = (i < N_NODES) ? cnt[i] : 0;
    #pragma unroll
    for (int off = 32; off; off >>= 1) v += __shfl_xor(v, off, 64);
    __shared__ int ws[4];
    if ((threadIdx.x & 63) == 0) ws[threadIdx.x >> 6] = v;
    __syncthreads();
    if (threadIdx.x == 0) bsum[blockIdx.x] = ws[0] + ws[1] + ws[2] + ws[3];
}
__global__ __launch_bounds__(512) void k_scanB(int* __restrict__ bsum){
    __shared__ int s[512];
    int t = threadIdx.x;
    int v = (t < NBLK) ? bsum[t] : 0;
    s[t] = v; __syncthreads();
    for (int off = 1; off < 512; off <<= 1){
        int u = (t >= off) ? s[t - off] : 0;
        __syncthreads();
        s[t] += u;
        __syncthreads();
    }
    if (t < NBLK) bsum[t] = s[t] - v;  // exclusive
}
__global__ __launch_bounds__(256) void k_scanC(const int* __restrict__ cnt, const int* __restrict__ bsum,
                                               int* __restrict__ rs, int* __restrict__ cur){
    __shared__ int s[256];
    int t = threadIdx.x;
    int i = blockIdx.x * 256 + t;
    int v = (i < N_NODES) ? cnt[i] : 0;
    s[t] = v; __syncthreads();
    for (int off = 1; off < 256; off <<= 1){
        int u = (t >= off) ? s[t - off] : 0;
        __syncthreads();
        s[t] += u;
        __syncthreads();
    }
    int pref = bsum[blockIdx.x] + s[t] - v;  // exclusive prefix
    if (i < N_NODES){ rs[i] = pref; cur[i] = pref; }
    if (i == N_NODES - 1) rs[N_NODES] = pref + v;
}
__global__ __launch_bounds__(256) void k_fill(const int* __restrict__ ei, int* __restrict__ cur,
                                              int* __restrict__ csr){
    int e = blockIdx.x * 256 + threadIdx.x;
    if (e < N_EDGES){
        int s = ei[e];
        int d = ei[N_EDGES + e];
        int pos = atomicAdd(&cur[d], 1);
        csr[pos] = s;
    }
}

// ---------------- node encoder: h = x @ Wenc + benc ----------------
__global__ __launch_bounds__(256) void k_enc(const float* __restrict__ x, const float* __restrict__ Wenc,
                                             const float* __restrict__ benc, float* __restrict__ h){
    __shared__ __align__(16) float sW[NODE_IN * H];
    __shared__ float sx[4][NODE_IN];
    int tid = threadIdx.x;
    int lane = tid & 63;
    int w = tid >> 6;
    int n = blockIdx.x * 4 + w;
    for (int i = tid; i < NODE_IN * H; i += 256) sW[i] = Wenc[i];
    if (n < N_NODES && lane < NODE_IN) sx[w][lane] = x[n * NODE_IN + lane];
    __syncthreads();
    if (n < N_NODES){
        float acc = benc[lane];
        #pragma unroll
        for (int k = 0; k < NODE_IN; ++k)
            acc = fmaf(sx[w][k], sW[k * H + lane], acc);
        h[n * H + lane] = acc;
    }
}

// ------------- fused SAGE layer: gather-reduce + GEMV + LN + GELU + residual -------------
#define SG_WAVES 8
__global__ __launch_bounds__(512) void k_sage(const float* __restrict__ h,
    const int* __restrict__ rs, const int* __restrict__ csr,
    const float* __restrict__ Wl, const float* __restrict__ bl, const float* __restrict__ Wr,
    const float* __restrict__ lng, const float* __restrict__ lnb,
    float* __restrict__ hout)
{
    __shared__ __align__(16) float sWl[H * 132];   // [f][k], k<128, stride 132 (odd in float4)
    __shared__ __align__(16) float sWr[H * 68];    // [f][k], k<64, stride 68
    __shared__ __align__(16) float sAggr[SG_WAVES][128];
    __shared__ __align__(16) float sH[SG_WAVES][64];
    int tid = threadIdx.x;
    for (int i = tid; i < 128 * H; i += 512){ int k = i >> 6, f = i & 63; sWl[f * 132 + k] = Wl[i]; }
    for (int i = tid; i < 64 * H;  i += 512){ int k = i >> 6, f = i & 63; sWr[f * 68 + k] = Wr[i]; }
    __syncthreads();
    int lane = tid & 63;
    int wv = tid >> 6;
    float blf = bl[lane], gf = lng[lane], bf = lnb[lane];
    int nw = gridDim.x * SG_WAVES;
    for (int n = blockIdx.x * SG_WAVES + wv; n < N_NODES; n += nw){
        int start = rs[n], end = rs[n + 1];
        float sumv = 0.f;
        float mxv = -INFINITY;
        for (int base = start; base < end; base += 64){
            int cnt = min(64, end - base);
            int sidx = (base + lane < end) ? csr[base + lane] : 0;
            int i = 0;
            for (; i + 4 <= cnt; i += 4){
                int s0 = __shfl(sidx, i, 64);
                int s1 = __shfl(sidx, i + 1, 64);
                int s2 = __shfl(sidx, i + 2, 64);
                int s3 = __shfl(sidx, i + 3, 64);
                float v0 = h[s0 * H + lane];
                float v1 = h[s1 * H + lane];
                float v2 = h[s2 * H + lane];
                float v3 = h[s3 * H + lane];
                sumv += (v0 + v1) + (v2 + v3);
                mxv = fmaxf(mxv, fmaxf(fmaxf(v0, v1), fmaxf(v2, v3)));
            }
            for (; i < cnt; ++i){
                int s = __shfl(sidx, i, 64);
                float v = h[s * H + lane];
                sumv += v;
                mxv = fmaxf(mxv, v);
            }
        }
        float dg = (float)(end - start);
        float hv = h[n * H + lane];
        float mean = (dg > 0.f) ? sumv / dg : 0.f;
        float mxo  = (dg > 0.f) ? mxv : 0.f;
        sAggr[wv][lane] = mean;
        sAggr[wv][64 + lane] = mxo;
        sH[wv][lane] = hv;
        asm volatile("s_waitcnt lgkmcnt(0)" ::: "memory");
        float acc = blf;
        const float4* aw = (const float4*)sAggr[wv];
        const float4* wl = (const float4*)(sWl + lane * 132);
        #pragma unroll
        for (int k4 = 0; k4 < 32; ++k4){
            float4 a = aw[k4]; float4 w = wl[k4];
            acc += a.x * w.x + a.y * w.y + a.z * w.z + a.w * w.w;
        }
        const float4* hw = (const float4*)sH[wv];
        const float4* wr = (const float4*)(sWr + lane * 68);
        #pragma unroll
        for (int k4 = 0; k4 < 16; ++k4){
            float4 a = hw[k4]; float4 w = wr[k4];
            acc += a.x * w.x + a.y * w.y + a.z * w.z + a.w * w.w;
        }
        float s1 = acc, s2 = acc * acc;
        #pragma unroll
        for (int off = 32; off; off >>= 1){
            s1 += __shfl_xor(s1, off, 64);
            s2 += __shfl_xor(s2, off, 64);
        }
        float mu_ = s1 * (1.f / 64.f);
        float var_ = s2 * (1.f / 64.f) - mu_ * mu_;
        float yv = (acc - mu_) * rsqrtf(var_ + LN_EPS) * gf + bf;
        hout[n * H + lane] = gelu_f(yv) + hv;
    }
}

// ------------- fused edge MLP: 2 queries per wave, register-pipelined gathers -------------
#define EM_WAVES 16
#define NPAIR (N_QUERY / 2)
__global__ __launch_bounds__(1024, 4) void k_mlp(const float* __restrict__ h,
    const int* __restrict__ qe, const float* __restrict__ ea,
    const float* __restrict__ W1, const float* __restrict__ b1,
    const float* __restrict__ bng, const float* __restrict__ bnb,
    const float* __restrict__ bnm, const float* __restrict__ bnv,
    const float* __restrict__ W2, const float* __restrict__ b2,
    const float* __restrict__ W3, const float* __restrict__ b3,
    float* __restrict__ out)
{
    __shared__ __align__(16) float sW1[128 * 140];   // [j][k], k<136, stride 140 (odd float4)
    __shared__ __align__(16) float sW2[64 * 132];    // [f][k], k<128, stride 132
    __shared__ __align__(16) float sZ[EM_WAVES][2][136];
    __shared__ __align__(16) float sZ1[EM_WAVES][2][128];
    int tid = threadIdx.x;
    for (int i = tid; i < 136 * 128; i += 1024){ int k = i >> 7, j = i & 127; sW1[j * 140 + k] = W1[i]; }
    for (int i = tid; i < 128 * 64;  i += 1024){ int k = i >> 6, f = i & 63; sW2[f * 132 + k] = W2[i]; }
    __syncthreads();
    int lane = tid & 63, wv = tid >> 6;
    int j1 = lane + 64;
    float b10 = b1[lane], b11 = b1[j1];
    float sc0 = bng[lane] * rsqrtf(bnv[lane] + BN_EPS);
    float sh0 = bnb[lane] - bnm[lane] * sc0;
    float sc1 = bng[j1] * rsqrtf(bnv[j1] + BN_EPS);
    float sh1 = bnb[j1] - bnm[j1] * sc1;
    float b2f = b2[lane], w3f = W3[lane], b3v = b3[0];
    int stride = gridDim.x * EM_WAVES;
    int p = blockIdx.x * EM_WAVES + wv;

    float ca = 0.f, cb = 0.f, cc = 0.f, cd = 0.f, ce = 0.f;
    if (p < NPAIR){
        int q0 = 2 * p, q1 = 2 * p + 1;
        int s0 = qe[q0], t0 = qe[N_QUERY + q0];
        int s1i = qe[q1], t1 = qe[N_QUERY + q1];
        ca = h[s0 * H + lane]; cb = h[t0 * H + lane];
        cc = h[s1i * H + lane]; cd = h[t1 * H + lane];
        ce = (lane < 16) ? ea[p * 16 + lane] : 0.f;
    }
    for (; p < NPAIR; p += stride){
        // stage current pair into LDS
        sZ[wv][0][lane] = ca;
        sZ[wv][0][64 + lane] = cb;
        sZ[wv][1][lane] = cc;
        sZ[wv][1][64 + lane] = cd;
        if (lane < 16) sZ[wv][lane >> 3][128 + (lane & 7)] = ce;
        asm volatile("s_waitcnt lgkmcnt(0)" ::: "memory");
        // prefetch next pair (hidden under compute)
        int pn = p + stride;
        if (pn < NPAIR){
            int q0 = 2 * pn, q1 = 2 * pn + 1;
            int s0 = qe[q0], t0 = qe[N_QUERY + q0];
            int s1i = qe[q1], t1 = qe[N_QUERY + q1];
            ca = h[s0 * H + lane]; cb = h[t0 * H + lane];
            cc = h[s1i * H + lane]; cd = h[t1 * H + lane];
            ce = (lane < 16) ? ea[pn * 16 + lane] : 0.f;
        }
        // layer 1: two queries share each weight read
        float a00 = b10, a01 = b11, a10 = b10, a11 = b11;
        const float4* za = (const float4*)sZ[wv][0];
        const float4* zb = (const float4*)sZ[wv][1];
        const float4* w1a = (const float4*)(sW1 + lane * 140);
        const float4* w1b = (const float4*)(sW1 + j1 * 140);
        #pragma unroll
        for (int k4 = 0; k4 < 34; ++k4){
            float4 z0 = za[k4], z1 = zb[k4];
            float4 wa = w1a[k4], wb = w1b[k4];
            a00 += z0.x * wa.x + z0.y * wa.y + z0.z * wa.z + z0.w * wa.w;
            a01 += z0.x * wb.x + z0.y * wb.y + z0.z * wb.z + z0.w * wb.w;
            a10 += z1.x * wa.x + z1.y * wa.y + z1.z * wa.z + z1.w * wa.w;
            a11 += z1.x * wb.x + z1.y * wb.y + z1.z * wb.z + z1.w * wb.w;
        }
        a00 = gelu_f(a00 * sc0 + sh0);
        a01 = gelu_f(a01 * sc1 + sh1);
        a10 = gelu_f(a10 * sc0 + sh0);
        a11 = gelu_f(a11 * sc1 + sh1);
        sZ1[wv][0][lane] = a00; sZ1[wv][0][j1] = a01;
        sZ1[wv][1][lane] = a10; sZ1[wv][1][j1] = a11;
        asm volatile("s_waitcnt lgkmcnt(0)" ::: "memory");
        // layer 2
        float c0 = b2f, c1 = b2f;
        const float4* z1a = (const float4*)sZ1[wv][0];
        const float4* z1b = (const float4*)sZ1[wv][1];
        const float4* w2 = (const float4*)(sW2 + lane * 132);
        #pragma unroll
        for (int k4 = 0; k4 < 32; ++k4){
            float4 u0 = z1a[k4], u1 = z1b[k4];
            float4 w = w2[k4];
            c0 += u0.x * w.x + u0.y * w.y + u0.z * w.z + u0.w * w.w;
            c1 += u1.x * w.x + u1.y * w.y + u1.z * w.z + u1.w * w.w;
        }
        c0 = gelu_f(c0);
        c1 = gelu_f(c1);
        float pv0 = c0 * w3f, pv1 = c1 * w3f;
        #pragma unroll
        for (int off = 32; off; off >>= 1){
            pv0 += __shfl_xor(pv0, off, 64);
            pv1 += __shfl_xor(pv1, off, 64);
        }
        if (lane == 0) ((float2*)out)[p] = make_float2(pv0 + b3v, pv1 + b3v);
    }
}

extern "C" void kernel_launch(void* const* d_in, const int* in_sizes, int n_in,
                              void* d_out, int out_size, void* d_ws, size_t ws_size,
                              hipStream_t stream) {
    const float* x    = (const float*)d_in[0];
    const int*   ei   = (const int*)d_in[1];
    const float* ea   = (const float*)d_in[2];
    const int*   qe   = (const int*)d_in[3];
    const float* Wenc = (const float*)d_in[4];
    const float* benc = (const float*)d_in[5];
    const float* Wl   = (const float*)d_in[6];
    const float* bl   = (const float*)d_in[7];
    const float* Wr   = (const float*)d_in[8];
    const float* lng  = (const float*)d_in[9];
    const float* lnb  = (const float*)d_in[10];
    const float* W1   = (const float*)d_in[11];
    const float* b1   = (const float*)d_in[12];
    const float* bng  = (const float*)d_in[13];
    const float* bnb  = (const float*)d_in[14];
    const float* bnm  = (const float*)d_in[15];
    const float* bnv  = (const float*)d_in[16];
    const float* W2   = (const float*)d_in[17];
    const float* b2   = (const float*)d_in[18];
    const float* W3   = (const float*)d_in[19];
    const float* b3   = (const float*)d_in[20];
    float* out = (float*)d_out;

    char* ws = (char*)d_ws;
    const size_t NH = (size_t)N_NODES * H;
    float* hA  = (float*)ws;  ws += NH * 4;
    float* hB  = (float*)ws;  ws += NH * 4;
    int*   cnt = (int*)ws;    ws += (size_t)N_NODES * 4;
    int*   rsb = (int*)ws;    ws += ((size_t)N_NODES + 4) * 4;
    int*   cur = (int*)ws;    ws += (size_t)N_NODES * 4;
    int*   csr = (int*)ws;    ws += (size_t)N_EDGES * 4;
    int*   bsum= (int*)ws;    ws += 512 * 4;

    // CSR build
    k_zero_cnt<<<NBLK, 256, 0, stream>>>(cnt);
    k_count<<<(N_EDGES + 255) / 256, 256, 0, stream>>>(ei, cnt);
    k_scanA<<<NBLK, 256, 0, stream>>>(cnt, bsum);
    k_scanB<<<1, 512, 0, stream>>>(bsum);
    k_scanC<<<NBLK, 256, 0, stream>>>(cnt, bsum, rsb, cur);
    k_fill<<<(N_EDGES + 255) / 256, 256, 0, stream>>>(ei, cur, csr);

    // encoder
    k_enc<<<(N_NODES + 3) / 4, 256, 0, stream>>>(x, Wenc, benc, hA);

    // SAGE layers
    float* hc = hA; float* hn = hB;
    for (int l = 0; l < LAYERS; ++l){
        k_sage<<<512, 512, 0, stream>>>(hc, rsb, csr,
            Wl + (size_t)l * 2 * H * H, bl + l * H, Wr + (size_t)l * H * H,
            lng + l * H, lnb + l * H, hn);
        float* tmp = hc; hc = hn; hn = tmp;
    }

    // edge MLP
    k_mlp<<<256, 1024, 0, stream>>>(hc, qe, ea, W1, b1, bng, bnb, bnm, bnv, W2, b2, W3, b3, out);
}

// Round 3
// 3637.306 us; speedup vs baseline: 2.8022x; 2.0666x over previous
//
#include <hip/hip_runtime.h>
#include <math.h>

#define N_NODES 100000
#define N_EDGES 1600000
#define N_QUERY 200000
#define NODE_IN 32
#define EDGE_IN 8
#define H 64
#define LAYERS 3
#define LN_EPS 1e-5f
#define BN_EPS 1e-5f
#define NBLK 391   // ceil(N_NODES/256)

__device__ __forceinline__ float gelu_f(float x){
    return 0.5f * x * (1.0f + erff(x * 0.70710678118654752440f));
}

// ---------------- CSR build ----------------
__global__ __launch_bounds__(256) void k_zero_cnt(int* __restrict__ c){
    int i = blockIdx.x * 256 + threadIdx.x;
    if (i < N_NODES) c[i] = 0;
}
__global__ __launch_bounds__(256) void k_count(const int* __restrict__ ei, int* __restrict__ c){
    int i = blockIdx.x * 256 + threadIdx.x;
    if (i < N_EDGES) atomicAdd(&c[ei[N_EDGES + i]], 1);
}
__global__ __launch_bounds__(256) void k_scanA(const int* __restrict__ cnt, int* __restrict__ bsum){
    int i = blockIdx.x * 256 + threadIdx.x;
    int v = (i < N_NODES) ? cnt[i] : 0;
    #pragma unroll
    for (int off = 32; off; off >>= 1) v += __shfl_xor(v, off, 64);
    __shared__ int ws[4];
    if ((threadIdx.x & 63) == 0) ws[threadIdx.x >> 6] = v;
    __syncthreads();
    if (threadIdx.x == 0) bsum[blockIdx.x] = ws[0] + ws[1] + ws[2] + ws[3];
}
__global__ __launch_bounds__(512) void k_scanB(int* __restrict__ bsum){
    __shared__ int s[512];
    int t = threadIdx.x;
    int v = (t < NBLK) ? bsum[t] : 0;
    s[t] = v; __syncthreads();
    for (int off = 1; off < 512; off <<= 1){
        int u = (t >= off) ? s[t - off] : 0;
        __syncthreads();
        s[t] += u;
        __syncthreads();
    }
    if (t < NBLK) bsum[t] = s[t] - v;  // exclusive
}
__global__ __launch_bounds__(256) void k_scanC(const int* __restrict__ cnt, const int* __restrict__ bsum,
                                               int* __restrict__ rs, int* __restrict__ cur){
    __shared__ int s[256];
    int t = threadIdx.x;
    int i = blockIdx.x * 256 + t;
    int v = (i < N_NODES) ? cnt[i] : 0;
    s[t] = v; __syncthreads();
    for (int off = 1; off < 256; off <<= 1){
        int u = (t >= off) ? s[t - off] : 0;
        __syncthreads();
        s[t] += u;
        __syncthreads();
    }
    int pref = bsum[blockIdx.x] + s[t] - v;  // exclusive prefix
    if (i < N_NODES){ rs[i] = pref; cur[i] = pref; }
    if (i == N_NODES - 1) rs[N_NODES] = pref + v;
}
__global__ __launch_bounds__(256) void k_fill(const int* __restrict__ ei, int* __restrict__ cur,
                                              int* __restrict__ csr){
    int e = blockIdx.x * 256 + threadIdx.x;
    if (e < N_EDGES){
        int s = ei[e];
        int d = ei[N_EDGES + e];
        int pos = atomicAdd(&cur[d], 1);
        csr[pos] = s;
    }
}

// ---------------- node encoder: h = x @ Wenc + benc ----------------
__global__ __launch_bounds__(256) void k_enc(const float* __restrict__ x, const float* __restrict__ Wenc,
                                             const float* __restrict__ benc, float* __restrict__ h){
    __shared__ __align__(16) float sW[NODE_IN * H];
    __shared__ float sx[4][NODE_IN];
    int tid = threadIdx.x;
    int lane = tid & 63;
    int w = tid >> 6;
    int n = blockIdx.x * 4 + w;
    for (int i = tid; i < NODE_IN * H; i += 256) sW[i] = Wenc[i];
    if (n < N_NODES && lane < NODE_IN) sx[w][lane] = x[n * NODE_IN + lane];
    __syncthreads();
    if (n < N_NODES){
        float acc = benc[lane];
        #pragma unroll
        for (int k = 0; k < NODE_IN; ++k)
            acc = fmaf(sx[w][k], sW[k * H + lane], acc);
        h[n * H + lane] = acc;
    }
}

// ------------- fused SAGE layer: gather-reduce + GEMV + LN + GELU + residual -------------
#define SG_WAVES 8
__global__ __launch_bounds__(512) void k_sage(const float* __restrict__ h,
    const int* __restrict__ rs, const int* __restrict__ csr,
    const float* __restrict__ Wl, const float* __restrict__ bl, const float* __restrict__ Wr,
    const float* __restrict__ lng, const float* __restrict__ lnb,
    float* __restrict__ hout)
{
    __shared__ __align__(16) float sWl[H * 132];   // [f][k], k<128, stride 132 (odd in float4)
    __shared__ __align__(16) float sWr[H * 68];    // [f][k], k<64, stride 68
    __shared__ __align__(16) float sAggr[SG_WAVES][128];
    __shared__ __align__(16) float sH[SG_WAVES][64];
    int tid = threadIdx.x;
    for (int i = tid; i < 128 * H; i += 512){ int k = i >> 6, f = i & 63; sWl[f * 132 + k] = Wl[i]; }
    for (int i = tid; i < 64 * H;  i += 512){ int k = i >> 6, f = i & 63; sWr[f * 68 + k] = Wr[i]; }
    __syncthreads();
    int lane = tid & 63;
    int wv = tid >> 6;
    float blf = bl[lane], gf = lng[lane], bf = lnb[lane];
    int nw = gridDim.x * SG_WAVES;
    for (int n = blockIdx.x * SG_WAVES + wv; n < N_NODES; n += nw){
        int start = rs[n], end = rs[n + 1];
        float sumv = 0.f;
        float mxv = -INFINITY;
        for (int base = start; base < end; base += 64){
            int cnt = min(64, end - base);
            int sidx = (base + lane < end) ? csr[base + lane] : 0;
            int i = 0;
            for (; i + 4 <= cnt; i += 4){
                int s0 = __shfl(sidx, i, 64);
                int s1 = __shfl(sidx, i + 1, 64);
                int s2 = __shfl(sidx, i + 2, 64);
                int s3 = __shfl(sidx, i + 3, 64);
                float v0 = h[s0 * H + lane];
                float v1 = h[s1 * H + lane];
                float v2 = h[s2 * H + lane];
                float v3 = h[s3 * H + lane];
                sumv += (v0 + v1) + (v2 + v3);
                mxv = fmaxf(mxv, fmaxf(fmaxf(v0, v1), fmaxf(v2, v3)));
            }
            for (; i < cnt; ++i){
                int s = __shfl(sidx, i, 64);
                float v = h[s * H + lane];
                sumv += v;
                mxv = fmaxf(mxv, v);
            }
        }
        float dg = (float)(end - start);
        float hv = h[n * H + lane];
        float mean = (dg > 0.f) ? sumv / dg : 0.f;
        float mxo  = (dg > 0.f) ? mxv : 0.f;
        sAggr[wv][lane] = mean;
        sAggr[wv][64 + lane] = mxo;
        sH[wv][lane] = hv;
        asm volatile("s_waitcnt lgkmcnt(0)" ::: "memory");
        float acc = blf;
        const float4* aw = (const float4*)sAggr[wv];
        const float4* wl = (const float4*)(sWl + lane * 132);
        #pragma unroll
        for (int k4 = 0; k4 < 32; ++k4){
            float4 a = aw[k4]; float4 w = wl[k4];
            acc += a.x * w.x + a.y * w.y + a.z * w.z + a.w * w.w;
        }
        const float4* hw = (const float4*)sH[wv];
        const float4* wr = (const float4*)(sWr + lane * 68);
        #pragma unroll
        for (int k4 = 0; k4 < 16; ++k4){
            float4 a = hw[k4]; float4 w = wr[k4];
            acc += a.x * w.x + a.y * w.y + a.z * w.z + a.w * w.w;
        }
        float s1 = acc, s2 = acc * acc;
        #pragma unroll
        for (int off = 32; off; off >>= 1){
            s1 += __shfl_xor(s1, off, 64);
            s2 += __shfl_xor(s2, off, 64);
        }
        float mu_ = s1 * (1.f / 64.f);
        float var_ = s2 * (1.f / 64.f) - mu_ * mu_;
        float yv = (acc - mu_) * rsqrtf(var_ + LN_EPS) * gf + bf;
        hout[n * H + lane] = gelu_f(yv) + hv;
    }
}

// ------------- fused edge MLP: 2 queries per wave, 512-thread blocks (no spills) -------------
#define EM_WAVES 8
#define NPAIR (N_QUERY / 2)
__global__ __launch_bounds__(512) void k_mlp(const float* __restrict__ h,
    const int* __restrict__ qe, const float* __restrict__ ea,
    const float* __restrict__ W1, const float* __restrict__ b1,
    const float* __restrict__ bng, const float* __restrict__ bnb,
    const float* __restrict__ bnm, const float* __restrict__ bnv,
    const float* __restrict__ W2, const float* __restrict__ b2,
    const float* __restrict__ W3, const float* __restrict__ b3,
    float* __restrict__ out)
{
    __shared__ __align__(16) float sW1[128 * 140];   // [j][k], k<136, stride 140 (2-way max on b128)
    __shared__ __align__(16) float sW2[64 * 132];    // [f][k], k<128, stride 132
    __shared__ __align__(16) float sZ[EM_WAVES][2][144];
    __shared__ __align__(16) float sZ1[EM_WAVES][2][128];
    int tid = threadIdx.x;
    for (int i = tid; i < 136 * 128; i += 512){ int k = i >> 7, j = i & 127; sW1[j * 140 + k] = W1[i]; }
    for (int i = tid; i < 128 * 64;  i += 512){ int k = i >> 6, f = i & 63; sW2[f * 132 + k] = W2[i]; }
    __syncthreads();
    int lane = tid & 63, wv = tid >> 6;
    int j1 = lane + 64;
    float b10 = b1[lane], b11 = b1[j1];
    float sc0 = bng[lane] * rsqrtf(bnv[lane] + BN_EPS);
    float sh0 = bnb[lane] - bnm[lane] * sc0;
    float sc1 = bng[j1] * rsqrtf(bnv[j1] + BN_EPS);
    float sh1 = bnb[j1] - bnm[j1] * sc1;
    float b2f = b2[lane], w3f = W3[lane], b3v = b3[0];
    int stride = gridDim.x * EM_WAVES;
    int p = blockIdx.x * EM_WAVES + wv;

    float ca = 0.f, cb = 0.f, cc = 0.f, cd = 0.f, ce = 0.f;
    if (p < NPAIR){
        int q0 = 2 * p, q1 = 2 * p + 1;
        int s0 = qe[q0], t0 = qe[N_QUERY + q0];
        int s1i = qe[q1], t1 = qe[N_QUERY + q1];
        ca = h[s0 * H + lane]; cb = h[t0 * H + lane];
        cc = h[s1i * H + lane]; cd = h[t1 * H + lane];
        ce = (lane < 16) ? ea[p * 16 + lane] : 0.f;
    }
    for (; p < NPAIR; p += stride){
        // stage current pair into LDS
        sZ[wv][0][lane] = ca;
        sZ[wv][0][64 + lane] = cb;
        sZ[wv][1][lane] = cc;
        sZ[wv][1][64 + lane] = cd;
        if (lane < 16) sZ[wv][lane >> 3][128 + (lane & 7)] = ce;
        asm volatile("s_waitcnt lgkmcnt(0)" ::: "memory");
        // prefetch next pair (hidden under compute)
        int pn = p + stride;
        if (pn < NPAIR){
            int q0 = 2 * pn, q1 = 2 * pn + 1;
            int s0 = qe[q0], t0 = qe[N_QUERY + q0];
            int s1i = qe[q1], t1 = qe[N_QUERY + q1];
            ca = h[s0 * H + lane]; cb = h[t0 * H + lane];
            cc = h[s1i * H + lane]; cd = h[t1 * H + lane];
            ce = (lane < 16) ? ea[pn * 16 + lane] : 0.f;
        }
        // layer 1: two queries share each weight read
        float a00 = b10, a01 = b11, a10 = b10, a11 = b11;
        const float4* za = (const float4*)sZ[wv][0];
        const float4* zb = (const float4*)sZ[wv][1];
        const float4* w1a = (const float4*)(sW1 + lane * 140);
        const float4* w1b = (const float4*)(sW1 + j1 * 140);
        #pragma unroll
        for (int k4 = 0; k4 < 34; ++k4){
            float4 z0 = za[k4], z1 = zb[k4];
            float4 wa = w1a[k4], wb = w1b[k4];
            a00 += z0.x * wa.x + z0.y * wa.y + z0.z * wa.z + z0.w * wa.w;
            a01 += z0.x * wb.x + z0.y * wb.y + z0.z * wb.z + z0.w * wb.w;
            a10 += z1.x * wa.x + z1.y * wa.y + z1.z * wa.z + z1.w * wa.w;
            a11 += z1.x * wb.x + z1.y * wb.y + z1.z * wb.z + z1.w * wb.w;
        }
        a00 = gelu_f(a00 * sc0 + sh0);
        a01 = gelu_f(a01 * sc1 + sh1);
        a10 = gelu_f(a10 * sc0 + sh0);
        a11 = gelu_f(a11 * sc1 + sh1);
        sZ1[wv][0][lane] = a00; sZ1[wv][0][j1] = a01;
        sZ1[wv][1][lane] = a10; sZ1[wv][1][j1] = a11;
        asm volatile("s_waitcnt lgkmcnt(0)" ::: "memory");
        // layer 2
        float c0 = b2f, c1 = b2f;
        const float4* z1a = (const float4*)sZ1[wv][0];
        const float4* z1b = (const float4*)sZ1[wv][1];
        const float4* w2 = (const float4*)(sW2 + lane * 132);
        #pragma unroll
        for (int k4 = 0; k4 < 32; ++k4){
            float4 u0 = z1a[k4], u1 = z1b[k4];
            float4 w = w2[k4];
            c0 += u0.x * w.x + u0.y * w.y + u0.z * w.z + u0.w * w.w;
            c1 += u1.x * w.x + u1.y * w.y + u1.z * w.z + u1.w * w.w;
        }
        c0 = gelu_f(c0);
        c1 = gelu_f(c1);
        float pv0 = c0 * w3f, pv1 = c1 * w3f;
        #pragma unroll
        for (int off = 32; off; off >>= 1){
            pv0 += __shfl_xor(pv0, off, 64);
            pv1 += __shfl_xor(pv1, off, 64);
        }
        if (lane == 0) ((float2*)out)[p] = make_float2(pv0 + b3v, pv1 + b3v);
    }
}

extern "C" void kernel_launch(void* const* d_in, const int* in_sizes, int n_in,
                              void* d_out, int out_size, void* d_ws, size_t ws_size,
                              hipStream_t stream) {
    const float* x    = (const float*)d_in[0];
    const int*   ei   = (const int*)d_in[1];
    const float* ea   = (const float*)d_in[2];
    const int*   qe   = (const int*)d_in[3];
    const float* Wenc = (const float*)d_in[4];
    const float* benc = (const float*)d_in[5];
    const float* Wl   = (const float*)d_in[6];
    const float* bl   = (const float*)d_in[7];
    const float* Wr   = (const float*)d_in[8];
    const float* lng  = (const float*)d_in[9];
    const float* lnb  = (const float*)d_in[10];
    const float* W1   = (const float*)d_in[11];
    const float* b1   = (const float*)d_in[12];
    const float* bng  = (const float*)d_in[13];
    const float* bnb  = (const float*)d_in[14];
    const float* bnm  = (const float*)d_in[15];
    const float* bnv  = (const float*)d_in[16];
    const float* W2   = (const float*)d_in[17];
    const float* b2   = (const float*)d_in[18];
    const float* W3   = (const float*)d_in[19];
    const float* b3   = (const float*)d_in[20];
    float* out = (float*)d_out;

    char* ws = (char*)d_ws;
    const size_t NH = (size_t)N_NODES * H;
    float* hA  = (float*)ws;  ws += NH * 4;
    float* hB  = (float*)ws;  ws += NH * 4;
    int*   cnt = (int*)ws;    ws += (size_t)N_NODES * 4;
    int*   rsb = (int*)ws;    ws += ((size_t)N_NODES + 4) * 4;
    int*   cur = (int*)ws;    ws += (size_t)N_NODES * 4;
    int*   csr = (int*)ws;    ws += (size_t)N_EDGES * 4;
    int*   bsum= (int*)ws;    ws += 512 * 4;

    // CSR build
    k_zero_cnt<<<NBLK, 256, 0, stream>>>(cnt);
    k_count<<<(N_EDGES + 255) / 256, 256, 0, stream>>>(ei, cnt);
    k_scanA<<<NBLK, 256, 0, stream>>>(cnt, bsum);
    k_scanB<<<1, 512, 0, stream>>>(bsum);
    k_scanC<<<NBLK, 256, 0, stream>>>(cnt, bsum, rsb, cur);
    k_fill<<<(N_EDGES + 255) / 256, 256, 0, stream>>>(ei, cur, csr);

    // encoder
    k_enc<<<(N_NODES + 3) / 4, 256, 0, stream>>>(x, Wenc, benc, hA);

    // SAGE layers
    float* hc = hA; float* hn = hB;
    for (int l = 0; l < LAYERS; ++l){
        k_sage<<<512, 512, 0, stream>>>(hc, rsb, csr,
            Wl + (size_t)l * 2 * H * H, bl + l * H, Wr + (size_t)l * H * H,
            lng + l * H, lnb + l * H, hn);
        float* tmp = hc; hc = hn; hn = tmp;
    }

    // edge MLP
    k_mlp<<<256, 512, 0, stream>>>(hc, qe, ea, W1, b1, bng, bnb, bnm, bnv, W2, b2, W3, b3, out);
}

// Round 4
// 975.027 us; speedup vs baseline: 10.4534x; 3.7305x over previous
//
#include <hip/hip_runtime.h>
#include <math.h>

#define N_NODES 100000
#define N_EDGES 1600000
#define N_QUERY 200000
#define NODE_IN 32
#define EDGE_IN 8
#define H 64
#define LAYERS 3
#define LN_EPS 1e-5f
#define BN_EPS 1e-5f
#define NBLK 391   // ceil(N_NODES/256)

__device__ __forceinline__ float gelu_f(float x){
    return 0.5f * x * (1.0f + erff(x * 0.70710678118654752440f));
}

// ---------------- CSR build ----------------
__global__ __launch_bounds__(256) void k_zero_cnt(int* __restrict__ c){
    int i = blockIdx.x * 256 + threadIdx.x;
    if (i < N_NODES) c[i] = 0;
}
__global__ __launch_bounds__(256) void k_count(const int* __restrict__ ei, int* __restrict__ c){
    int i = blockIdx.x * 256 + threadIdx.x;
    if (i < N_EDGES) atomicAdd(&c[ei[N_EDGES + i]], 1);
}
__global__ __launch_bounds__(256) void k_scanA(const int* __restrict__ cnt, int* __restrict__ bsum){
    int i = blockIdx.x * 256 + threadIdx.x;
    int v = (i < N_NODES) ? cnt[i] : 0;
    #pragma unroll
    for (int off = 32; off; off >>= 1) v += __shfl_xor(v, off, 64);
    __shared__ int ws[4];
    if ((threadIdx.x & 63) == 0) ws[threadIdx.x >> 6] = v;
    __syncthreads();
    if (threadIdx.x == 0) bsum[blockIdx.x] = ws[0] + ws[1] + ws[2] + ws[3];
}
__global__ __launch_bounds__(512) void k_scanB(int* __restrict__ bsum){
    __shared__ int s[512];
    int t = threadIdx.x;
    int v = (t < NBLK) ? bsum[t] : 0;
    s[t] = v; __syncthreads();
    for (int off = 1; off < 512; off <<= 1){
        int u = (t >= off) ? s[t - off] : 0;
        __syncthreads();
        s[t] += u;
        __syncthreads();
    }
    if (t < NBLK) bsum[t] = s[t] - v;  // exclusive
}
__global__ __launch_bounds__(256) void k_scanC(const int* __restrict__ cnt, const int* __restrict__ bsum,
                                               int* __restrict__ rs, int* __restrict__ cur){
    __shared__ int s[256];
    int t = threadIdx.x;
    int i = blockIdx.x * 256 + t;
    int v = (i < N_NODES) ? cnt[i] : 0;
    s[t] = v; __syncthreads();
    for (int off = 1; off < 256; off <<= 1){
        int u = (t >= off) ? s[t - off] : 0;
        __syncthreads();
        s[t] += u;
        __syncthreads();
    }
    int pref = bsum[blockIdx.x] + s[t] - v;  // exclusive prefix
    if (i < N_NODES){ rs[i] = pref; cur[i] = pref; }
    if (i == N_NODES - 1) rs[N_NODES] = pref + v;
}
__global__ __launch_bounds__(256) void k_fill(const int* __restrict__ ei, int* __restrict__ cur,
                                              int* __restrict__ csr){
    int e = blockIdx.x * 256 + threadIdx.x;
    if (e < N_EDGES){
        int s = ei[e];
        int d = ei[N_EDGES + e];
        int pos = atomicAdd(&cur[d], 1);
        csr[pos] = s;
    }
}

// ---------------- node encoder: h = x @ Wenc + benc ----------------
__global__ __launch_bounds__(256) void k_enc(const float* __restrict__ x, const float* __restrict__ Wenc,
                                             const float* __restrict__ benc, float* __restrict__ h){
    __shared__ __align__(16) float sW[NODE_IN * H];
    __shared__ float sx[4][NODE_IN];
    int tid = threadIdx.x;
    int lane = tid & 63;
    int w = tid >> 6;
    int n = blockIdx.x * 4 + w;
    for (int i = tid; i < NODE_IN * H; i += 256) sW[i] = Wenc[i];
    if (n < N_NODES && lane < NODE_IN) sx[w][lane] = x[n * NODE_IN + lane];
    __syncthreads();
    if (n < N_NODES){
        float acc = benc[lane];
        #pragma unroll
        for (int k = 0; k < NODE_IN; ++k)
            acc = fmaf(sx[w][k], sW[k * H + lane], acc);
        h[n * H + lane] = acc;
    }
}

// ------------- fused SAGE layer: gather-reduce + GEMV + LN + GELU + residual -------------
#define SG_WAVES 8
__global__ __launch_bounds__(512) void k_sage(const float* __restrict__ h,
    const int* __restrict__ rs, const int* __restrict__ csr,
    const float* __restrict__ Wl, const float* __restrict__ bl, const float* __restrict__ Wr,
    const float* __restrict__ lng, const float* __restrict__ lnb,
    float* __restrict__ hout)
{
    __shared__ __align__(16) float sWl[H * 132];   // [f][k], k<128, stride 132 (odd in float4)
    __shared__ __align__(16) float sWr[H * 68];    // [f][k], k<64, stride 68
    __shared__ __align__(16) float sAggr[SG_WAVES][128];
    __shared__ __align__(16) float sH[SG_WAVES][64];
    int tid = threadIdx.x;
    for (int i = tid; i < 128 * H; i += 512){ int k = i >> 6, f = i & 63; sWl[f * 132 + k] = Wl[i]; }
    for (int i = tid; i < 64 * H;  i += 512){ int k = i >> 6, f = i & 63; sWr[f * 68 + k] = Wr[i]; }
    __syncthreads();
    int lane = tid & 63;
    int wv = tid >> 6;
    float blf = bl[lane], gf = lng[lane], bf = lnb[lane];
    int nw = gridDim.x * SG_WAVES;
    for (int n = blockIdx.x * SG_WAVES + wv; n < N_NODES; n += nw){
        int start = rs[n], end = rs[n + 1];
        float sumv = 0.f;
        float mxv = -INFINITY;
        for (int base = start; base < end; base += 64){
            int cnt = min(64, end - base);
            int sidx = (base + lane < end) ? csr[base + lane] : 0;
            int i = 0;
            for (; i + 4 <= cnt; i += 4){
                int s0 = __shfl(sidx, i, 64);
                int s1 = __shfl(sidx, i + 1, 64);
                int s2 = __shfl(sidx, i + 2, 64);
                int s3 = __shfl(sidx, i + 3, 64);
                float v0 = h[s0 * H + lane];
                float v1 = h[s1 * H + lane];
                float v2 = h[s2 * H + lane];
                float v3 = h[s3 * H + lane];
                sumv += (v0 + v1) + (v2 + v3);
                mxv = fmaxf(mxv, fmaxf(fmaxf(v0, v1), fmaxf(v2, v3)));
            }
            for (; i < cnt; ++i){
                int s = __shfl(sidx, i, 64);
                float v = h[s * H + lane];
                sumv += v;
                mxv = fmaxf(mxv, v);
            }
        }
        float dg = (float)(end - start);
        float hv = h[n * H + lane];
        float mean = (dg > 0.f) ? sumv / dg : 0.f;
        float mxo  = (dg > 0.f) ? mxv : 0.f;
        sAggr[wv][lane] = mean;
        sAggr[wv][64 + lane] = mxo;
        sH[wv][lane] = hv;
        asm volatile("s_waitcnt lgkmcnt(0)" ::: "memory");
        float acc = blf;
        const float4* aw = (const float4*)sAggr[wv];
        const float4* wl = (const float4*)(sWl + lane * 132);
        #pragma unroll 4
        for (int k4 = 0; k4 < 32; ++k4){
            float4 a = aw[k4]; float4 w = wl[k4];
            acc += a.x * w.x + a.y * w.y + a.z * w.z + a.w * w.w;
        }
        const float4* hw = (const float4*)sH[wv];
        const float4* wr = (const float4*)(sWr + lane * 68);
        #pragma unroll 4
        for (int k4 = 0; k4 < 16; ++k4){
            float4 a = hw[k4]; float4 w = wr[k4];
            acc += a.x * w.x + a.y * w.y + a.z * w.z + a.w * w.w;
        }
        float s1 = acc, s2 = acc * acc;
        #pragma unroll
        for (int off = 32; off; off >>= 1){
            s1 += __shfl_xor(s1, off, 64);
            s2 += __shfl_xor(s2, off, 64);
        }
        float mu_ = s1 * (1.f / 64.f);
        float var_ = s2 * (1.f / 64.f) - mu_ * mu_;
        float yv = (acc - mu_) * rsqrtf(var_ + LN_EPS) * gf + bf;
        hout[n * H + lane] = gelu_f(yv) + hv;
    }
}

// ------------- fused edge MLP: 2 queries per wave, capped unroll (no spills) -------------
#define EM_WAVES 8
#define NPAIR (N_QUERY / 2)
__global__ __launch_bounds__(512, 2) void k_mlp(const float* __restrict__ h,
    const int* __restrict__ qe, const float* __restrict__ ea,
    const float* __restrict__ W1, const float* __restrict__ b1,
    const float* __restrict__ bng, const float* __restrict__ bnb,
    const float* __restrict__ bnm, const float* __restrict__ bnv,
    const float* __restrict__ W2, const float* __restrict__ b2,
    const float* __restrict__ W3, const float* __restrict__ b3,
    float* __restrict__ out)
{
    __shared__ __align__(16) float sW1[128 * 140];   // [j][k], k<136, stride 140
    __shared__ __align__(16) float sW2[64 * 132];    // [f][k], k<128, stride 132
    __shared__ __align__(16) float sZ[EM_WAVES][2][144];
    __shared__ __align__(16) float sZ1[EM_WAVES][2][128];
    int tid = threadIdx.x;
    for (int i = tid; i < 136 * 128; i += 512){ int k = i >> 7, j = i & 127; sW1[j * 140 + k] = W1[i]; }
    for (int i = tid; i < 128 * 64;  i += 512){ int k = i >> 6, f = i & 63; sW2[f * 132 + k] = W2[i]; }
    __syncthreads();
    int lane = tid & 63, wv = tid >> 6;
    int j1 = lane + 64;
    float b10 = b1[lane], b11 = b1[j1];
    float sc0 = bng[lane] * rsqrtf(bnv[lane] + BN_EPS);
    float sh0 = bnb[lane] - bnm[lane] * sc0;
    float sc1 = bng[j1] * rsqrtf(bnv[j1] + BN_EPS);
    float sh1 = bnb[j1] - bnm[j1] * sc1;
    float b2f = b2[lane], w3f = W3[lane], b3v = b3[0];
    int stride = gridDim.x * EM_WAVES;
    int p = blockIdx.x * EM_WAVES + wv;

    float ca = 0.f, cb = 0.f, cc = 0.f, cd = 0.f, ce = 0.f;
    if (p < NPAIR){
        int q0 = 2 * p, q1 = 2 * p + 1;
        int s0 = qe[q0], t0 = qe[N_QUERY + q0];
        int s1i = qe[q1], t1 = qe[N_QUERY + q1];
        ca = h[s0 * H + lane]; cb = h[t0 * H + lane];
        cc = h[s1i * H + lane]; cd = h[t1 * H + lane];
        ce = (lane < 16) ? ea[p * 16 + lane] : 0.f;
    }
    for (; p < NPAIR; p += stride){
        // stage current pair into LDS
        sZ[wv][0][lane] = ca;
        sZ[wv][0][64 + lane] = cb;
        sZ[wv][1][lane] = cc;
        sZ[wv][1][64 + lane] = cd;
        if (lane < 16) sZ[wv][lane >> 3][128 + (lane & 7)] = ce;
        asm volatile("s_waitcnt lgkmcnt(0)" ::: "memory");
        // prefetch next pair (hidden under compute)
        int pn = p + stride;
        if (pn < NPAIR){
            int q0 = 2 * pn, q1 = 2 * pn + 1;
            int s0 = qe[q0], t0 = qe[N_QUERY + q0];
            int s1i = qe[q1], t1 = qe[N_QUERY + q1];
            ca = h[s0 * H + lane]; cb = h[t0 * H + lane];
            cc = h[s1i * H + lane]; cd = h[t1 * H + lane];
            ce = (lane < 16) ? ea[pn * 16 + lane] : 0.f;
        }
        // layer 1: two queries share each weight read; unroll capped to bound live regs
        float a00 = b10, a01 = b11, a10 = b10, a11 = b11;
        const float4* za = (const float4*)sZ[wv][0];
        const float4* zb = (const float4*)sZ[wv][1];
        const float4* w1a = (const float4*)(sW1 + lane * 140);
        const float4* w1b = (const float4*)(sW1 + j1 * 140);
        #pragma unroll 4
        for (int k4 = 0; k4 < 34; ++k4){
            float4 z0 = za[k4], z1 = zb[k4];
            float4 wa = w1a[k4], wb = w1b[k4];
            a00 += z0.x * wa.x + z0.y * wa.y + z0.z * wa.z + z0.w * wa.w;
            a01 += z0.x * wb.x + z0.y * wb.y + z0.z * wb.z + z0.w * wb.w;
            a10 += z1.x * wa.x + z1.y * wa.y + z1.z * wa.z + z1.w * wa.w;
            a11 += z1.x * wb.x + z1.y * wb.y + z1.z * wb.z + z1.w * wb.w;
        }
        a00 = gelu_f(a00 * sc0 + sh0);
        a01 = gelu_f(a01 * sc1 + sh1);
        a10 = gelu_f(a10 * sc0 + sh0);
        a11 = gelu_f(a11 * sc1 + sh1);
        sZ1[wv][0][lane] = a00; sZ1[wv][0][j1] = a01;
        sZ1[wv][1][lane] = a10; sZ1[wv][1][j1] = a11;
        asm volatile("s_waitcnt lgkmcnt(0)" ::: "memory");
        // layer 2
        float c0 = b2f, c1 = b2f;
        const float4* z1a = (const float4*)sZ1[wv][0];
        const float4* z1b = (const float4*)sZ1[wv][1];
        const float4* w2 = (const float4*)(sW2 + lane * 132);
        #pragma unroll 4
        for (int k4 = 0; k4 < 32; ++k4){
            float4 u0 = z1a[k4], u1 = z1b[k4];
            float4 w = w2[k4];
            c0 += u0.x * w.x + u0.y * w.y + u0.z * w.z + u0.w * w.w;
            c1 += u1.x * w.x + u1.y * w.y + u1.z * w.z + u1.w * w.w;
        }
        c0 = gelu_f(c0);
        c1 = gelu_f(c1);
        float pv0 = c0 * w3f, pv1 = c1 * w3f;
        #pragma unroll
        for (int off = 32; off; off >>= 1){
            pv0 += __shfl_xor(pv0, off, 64);
            pv1 += __shfl_xor(pv1, off, 64);
        }
        if (lane == 0) ((float2*)out)[p] = make_float2(pv0 + b3v, pv1 + b3v);
    }
}

extern "C" void kernel_launch(void* const* d_in, const int* in_sizes, int n_in,
                              void* d_out, int out_size, void* d_ws, size_t ws_size,
                              hipStream_t stream) {
    const float* x    = (const float*)d_in[0];
    const int*   ei   = (const int*)d_in[1];
    const float* ea   = (const float*)d_in[2];
    const int*   qe   = (const int*)d_in[3];
    const float* Wenc = (const float*)d_in[4];
    const float* benc = (const float*)d_in[5];
    const float* Wl   = (const float*)d_in[6];
    const float* bl   = (const float*)d_in[7];
    const float* Wr   = (const float*)d_in[8];
    const float* lng  = (const float*)d_in[9];
    const float* lnb  = (const float*)d_in[10];
    const float* W1   = (const float*)d_in[11];
    const float* b1   = (const float*)d_in[12];
    const float* bng  = (const float*)d_in[13];
    const float* bnb  = (const float*)d_in[14];
    const float* bnm  = (const float*)d_in[15];
    const float* bnv  = (const float*)d_in[16];
    const float* W2   = (const float*)d_in[17];
    const float* b2   = (const float*)d_in[18];
    const float* W3   = (const float*)d_in[19];
    const float* b3   = (const float*)d_in[20];
    float* out = (float*)d_out;

    char* ws = (char*)d_ws;
    const size_t NH = (size_t)N_NODES * H;
    float* hA  = (float*)ws;  ws += NH * 4;
    float* hB  = (float*)ws;  ws += NH * 4;
    int*   cnt = (int*)ws;    ws += (size_t)N_NODES * 4;
    int*   rsb = (int*)ws;    ws += ((size_t)N_NODES + 4) * 4;
    int*   cur = (int*)ws;    ws += (size_t)N_NODES * 4;
    int*   csr = (int*)ws;    ws += (size_t)N_EDGES * 4;
    int*   bsum= (int*)ws;    ws += 512 * 4;

    // CSR build
    k_zero_cnt<<<NBLK, 256, 0, stream>>>(cnt);
    k_count<<<(N_EDGES + 255) / 256, 256, 0, stream>>>(ei, cnt);
    k_scanA<<<NBLK, 256, 0, stream>>>(cnt, bsum);
    k_scanB<<<1, 512, 0, stream>>>(bsum);
    k_scanC<<<NBLK, 256, 0, stream>>>(cnt, bsum, rsb, cur);
    k_fill<<<(N_EDGES + 255) / 256, 256, 0, stream>>>(ei, cur, csr);

    // encoder
    k_enc<<<(N_NODES + 3) / 4, 256, 0, stream>>>(x, Wenc, benc, hA);

    // SAGE layers
    float* hc = hA; float* hn = hB;
    for (int l = 0; l < LAYERS; ++l){
        k_sage<<<512, 512, 0, stream>>>(hc, rsb, csr,
            Wl + (size_t)l * 2 * H * H, bl + l * H, Wr + (size_t)l * H * H,
            lng + l * H, lnb + l * H, hn);
        float* tmp = hc; hc = hn; hn = tmp;
    }

    // edge MLP
    k_mlp<<<256, 512, 0, stream>>>(hc, qe, ea, W1, b1, bng, bnb, bnm, bnv, W2, b2, W3, b3, out);
}

// Round 5
// 732.588 us; speedup vs baseline: 13.9128x; 1.3309x over previous
//
#include <hip/hip_runtime.h>
#include <math.h>

#define N_NODES 100000
#define N_EDGES 1600000
#define N_QUERY 200000
#define NODE_IN 32
#define EDGE_IN 8
#define H 64
#define LAYERS 3
#define LN_EPS 1e-5f
#define BN_EPS 1e-5f
#define NBLK 391   // ceil(N_NODES/256)

typedef __attribute__((ext_vector_type(8))) short short8b;
typedef __attribute__((ext_vector_type(4))) float f32x4;

__device__ __forceinline__ float gelu_f(float x){
    return 0.5f * x * (1.0f + erff(x * 0.70710678118654752440f));
}
__device__ __forceinline__ ushort f2bf(float x){  // RNE f32->bf16
    unsigned u = __float_as_uint(x);
    unsigned r = (u + 0x7FFFu + ((u >> 16) & 1u)) >> 16;
    return (ushort)r;
}

// ---------------- CSR build ----------------
__global__ __launch_bounds__(256) void k_zero_cnt(int* __restrict__ c){
    int i = blockIdx.x * 256 + threadIdx.x;
    if (i < N_NODES) c[i] = 0;
}
__global__ __launch_bounds__(256) void k_count(const int* __restrict__ ei, int* __restrict__ c){
    int i = blockIdx.x * 256 + threadIdx.x;
    if (i < N_EDGES) atomicAdd(&c[ei[N_EDGES + i]], 1);
}
__global__ __launch_bounds__(256) void k_scanA(const int* __restrict__ cnt, int* __restrict__ bsum){
    int i = blockIdx.x * 256 + threadIdx.x;
    int v = (i < N_NODES) ? cnt[i] : 0;
    #pragma unroll
    for (int off = 32; off; off >>= 1) v += __shfl_xor(v, off, 64);
    __shared__ int ws[4];
    if ((threadIdx.x & 63) == 0) ws[threadIdx.x >> 6] = v;
    __syncthreads();
    if (threadIdx.x == 0) bsum[blockIdx.x] = ws[0] + ws[1] + ws[2] + ws[3];
}
__global__ __launch_bounds__(512) void k_scanB(int* __restrict__ bsum){
    __shared__ int s[512];
    int t = threadIdx.x;
    int v = (t < NBLK) ? bsum[t] : 0;
    s[t] = v; __syncthreads();
    for (int off = 1; off < 512; off <<= 1){
        int u = (t >= off) ? s[t - off] : 0;
        __syncthreads();
        s[t] += u;
        __syncthreads();
    }
    if (t < NBLK) bsum[t] = s[t] - v;  // exclusive
}
__global__ __launch_bounds__(256) void k_scanC(const int* __restrict__ cnt, const int* __restrict__ bsum,
                                               int* __restrict__ rs, int* __restrict__ cur){
    __shared__ int s[256];
    int t = threadIdx.x;
    int i = blockIdx.x * 256 + t;
    int v = (i < N_NODES) ? cnt[i] : 0;
    s[t] = v; __syncthreads();
    for (int off = 1; off < 256; off <<= 1){
        int u = (t >= off) ? s[t - off] : 0;
        __syncthreads();
        s[t] += u;
        __syncthreads();
    }
    int pref = bsum[blockIdx.x] + s[t] - v;  // exclusive prefix
    if (i < N_NODES){ rs[i] = pref; cur[i] = pref; }
    if (i == N_NODES - 1) rs[N_NODES] = pref + v;
}
__global__ __launch_bounds__(256) void k_fill(const int* __restrict__ ei, int* __restrict__ cur,
                                              int* __restrict__ csr){
    int e = blockIdx.x * 256 + threadIdx.x;
    if (e < N_EDGES){
        int s = ei[e];
        int d = ei[N_EDGES + e];
        int pos = atomicAdd(&cur[d], 1);
        csr[pos] = s;
    }
}

// ---------------- node encoder: h = x @ Wenc + benc ----------------
__global__ __launch_bounds__(256) void k_enc(const float* __restrict__ x, const float* __restrict__ Wenc,
                                             const float* __restrict__ benc, float* __restrict__ h){
    __shared__ __align__(16) float sW[NODE_IN * H];
    __shared__ float sx[4][NODE_IN];
    int tid = threadIdx.x;
    int lane = tid & 63;
    int w = tid >> 6;
    int n = blockIdx.x * 4 + w;
    for (int i = tid; i < NODE_IN * H; i += 256) sW[i] = Wenc[i];
    if (n < N_NODES && lane < NODE_IN) sx[w][lane] = x[n * NODE_IN + lane];
    __syncthreads();
    if (n < N_NODES){
        float acc = benc[lane];
        #pragma unroll
        for (int k = 0; k < NODE_IN; ++k)
            acc = fmaf(sx[w][k], sW[k * H + lane], acc);
        h[n * H + lane] = acc;
    }
}

// ------------- fused SAGE layer: gather-reduce + GEMV + LN + GELU + residual -------------
#define SG_WAVES 8
__global__ __launch_bounds__(512) void k_sage(const float* __restrict__ h,
    const int* __restrict__ rs, const int* __restrict__ csr,
    const float* __restrict__ Wl, const float* __restrict__ bl, const float* __restrict__ Wr,
    const float* __restrict__ lng, const float* __restrict__ lnb,
    float* __restrict__ hout)
{
    __shared__ __align__(16) float sWl[H * 132];   // [f][k], k<128, stride 132
    __shared__ __align__(16) float sWr[H * 68];    // [f][k], k<64, stride 68
    __shared__ __align__(16) float sAggr[SG_WAVES][128];
    __shared__ __align__(16) float sH[SG_WAVES][64];
    int tid = threadIdx.x;
    for (int i = tid; i < 128 * H; i += 512){ int k = i >> 6, f = i & 63; sWl[f * 132 + k] = Wl[i]; }
    for (int i = tid; i < 64 * H;  i += 512){ int k = i >> 6, f = i & 63; sWr[f * 68 + k] = Wr[i]; }
    __syncthreads();
    int lane = tid & 63;
    int wv = tid >> 6;
    float blf = bl[lane], gf = lng[lane], bf = lnb[lane];
    int nw = gridDim.x * SG_WAVES;
    for (int n = blockIdx.x * SG_WAVES + wv; n < N_NODES; n += nw){
        int start = rs[n], end = rs[n + 1];
        float sumv = 0.f;
        float mxv = -INFINITY;
        for (int base = start; base < end; base += 64){
            int cnt = min(64, end - base);
            int sidx = (base + lane < end) ? csr[base + lane] : 0;
            int i = 0;
            for (; i + 4 <= cnt; i += 4){
                int s0 = __shfl(sidx, i, 64);
                int s1 = __shfl(sidx, i + 1, 64);
                int s2 = __shfl(sidx, i + 2, 64);
                int s3 = __shfl(sidx, i + 3, 64);
                float v0 = h[s0 * H + lane];
                float v1 = h[s1 * H + lane];
                float v2 = h[s2 * H + lane];
                float v3 = h[s3 * H + lane];
                sumv += (v0 + v1) + (v2 + v3);
                mxv = fmaxf(mxv, fmaxf(fmaxf(v0, v1), fmaxf(v2, v3)));
            }
            for (; i < cnt; ++i){
                int s = __shfl(sidx, i, 64);
                float v = h[s * H + lane];
                sumv += v;
                mxv = fmaxf(mxv, v);
            }
        }
        float dg = (float)(end - start);
        float hv = h[n * H + lane];
        float mean = (dg > 0.f) ? sumv / dg : 0.f;
        float mxo  = (dg > 0.f) ? mxv : 0.f;
        sAggr[wv][lane] = mean;
        sAggr[wv][64 + lane] = mxo;
        sH[wv][lane] = hv;
        asm volatile("s_waitcnt lgkmcnt(0)" ::: "memory");
        float acc = blf;
        const float4* aw = (const float4*)sAggr[wv];
        const float4* wl = (const float4*)(sWl + lane * 132);
        #pragma unroll 4
        for (int k4 = 0; k4 < 32; ++k4){
            float4 a = aw[k4]; float4 w = wl[k4];
            acc += a.x * w.x + a.y * w.y + a.z * w.z + a.w * w.w;
        }
        const float4* hw = (const float4*)sH[wv];
        const float4* wr = (const float4*)(sWr + lane * 68);
        #pragma unroll 4
        for (int k4 = 0; k4 < 16; ++k4){
            float4 a = hw[k4]; float4 w = wr[k4];
            acc += a.x * w.x + a.y * w.y + a.z * w.z + a.w * w.w;
        }
        float s1 = acc, s2 = acc * acc;
        #pragma unroll
        for (int off = 32; off; off >>= 1){
            s1 += __shfl_xor(s1, off, 64);
            s2 += __shfl_xor(s2, off, 64);
        }
        float mu_ = s1 * (1.f / 64.f);
        float var_ = s2 * (1.f / 64.f) - mu_ * mu_;
        float yv = (acc - mu_) * rsqrtf(var_ + LN_EPS) * gf + bf;
        hout[n * H + lane] = gelu_f(yv) + hv;
    }
}

// ------------- MFMA edge MLP: 128 queries/block, bf16 matrix cores -------------
// LDS: sZ [128][168] bf16 (43008B), sWa/sWb [128][72] bf16 (18432B each) = 79872B -> 2 blocks/CU
#define QB 128
__global__ __launch_bounds__(512, 2) void k_mlp_mfma(const float* __restrict__ h,
    const int* __restrict__ qe, const float* __restrict__ ea,
    const float* __restrict__ W1, const float* __restrict__ b1,
    const float* __restrict__ bng, const float* __restrict__ bnb,
    const float* __restrict__ bnm, const float* __restrict__ bnv,
    const float* __restrict__ W2, const float* __restrict__ b2,
    const float* __restrict__ W3, const float* __restrict__ b3,
    float* __restrict__ out)
{
    __shared__ __align__(16) ushort sZ[QB * 168];
    __shared__ __align__(16) ushort sWa[128 * 72];
    __shared__ __align__(16) ushort sWb[128 * 72];
    const int tid = threadIdx.x;
    const int lane = tid & 63;
    const int w = tid >> 6;          // wave 0..7 = M-tile
    const int l15 = lane & 15;
    const int kb = lane >> 4;        // k-block 0..3
    const int q0 = blockIdx.x * QB;

    // ---- stage z: 4 threads per query ----
    {
        int tq = tid >> 2;           // query row in block
        int part = tid & 3;
        int q = q0 + tq;
        int qs = (q < N_QUERY) ? q : 0;
        int sidx = qe[qs], tidx = qe[N_QUERY + qs];
        const float4* src = (part < 2) ? (const float4*)(h + (size_t)sidx * H + part * 32)
                                       : (const float4*)(h + (size_t)tidx * H + (part - 2) * 32);
        ushort* dst = sZ + tq * 168 + part * 32;
        #pragma unroll
        for (int i = 0; i < 8; ++i){
            float4 v = src[i];
            ushort4 o = { f2bf(v.x), f2bf(v.y), f2bf(v.z), f2bf(v.w) };
            *(ushort4*)(dst + i * 4) = o;
        }
        if (part == 0){
            const float4* ep = (const float4*)(ea + (size_t)qs * 8);
            float4 e0 = ep[0], e1 = ep[1];
            ushort4 o0 = { f2bf(e0.x), f2bf(e0.y), f2bf(e0.z), f2bf(e0.w) };
            ushort4 o1 = { f2bf(e1.x), f2bf(e1.y), f2bf(e1.z), f2bf(e1.w) };
            *(ushort4*)(sZ + tq * 168 + 128) = o0;
            *(ushort4*)(sZ + tq * 168 + 132) = o1;
        } else {
            ushort4 zz = { 0, 0, 0, 0 };
            ushort* zp = sZ + tq * 168 + 136 + (part - 1) * 8;  // parts 1,2,3 cover k=136..159
            *(ushort4*)(zp) = zz;
            *(ushort4*)(zp + 4) = zz;
        }
        if (part == 3){  // k=160..167
            ushort4 zz = { 0, 0, 0, 0 };
            *(ushort4*)(sZ + tq * 168 + 160) = zz;
            *(ushort4*)(sZ + tq * 168 + 164) = zz;
        }
    }
    // ---- stage W1 chunks c0 (k=0..63) -> sWa, c1 (k=64..127) -> sWb ----
    for (int it = 0; it < 16; ++it){
        int idx = tid + it * 512;            // 8192
        int j = idx & 127, kl = idx >> 7;
        sWa[j * 72 + kl] = f2bf(W1[(kl) * 128 + j]);
        sWb[j * 72 + kl] = f2bf(W1[(64 + kl) * 128 + j]);
    }
    __syncthreads();

    // ---- layer1 MFMA: k chunks 0,32 (Wa) and 64,96 (Wb) ----
    f32x4 acc[8];
    #pragma unroll
    for (int n = 0; n < 8; ++n) acc[n] = (f32x4){0.f, 0.f, 0.f, 0.f};
    const int arow = (w * 16 + l15) * 168 + kb * 8;
    #pragma unroll
    for (int s = 0; s < 4; ++s){
        const ushort* wbuf = (s < 2) ? sWa : sWb;
        int kg = s * 32;
        int kl = (s & 1) * 32;
        short8b a = *(const short8b*)(sZ + arow + kg);
        #pragma unroll
        for (int n = 0; n < 8; ++n){
            short8b b = *(const short8b*)(wbuf + (n * 16 + l15) * 72 + kl + kb * 8);
            acc[n] = __builtin_amdgcn_mfma_f32_16x16x32_bf16(a, b, acc[n], 0, 0, 0);
        }
    }
    __syncthreads();
    // ---- stage W1 chunk c2 (k=128..159, zero-pad >=136) -> sWa ; W2^T -> sWb ----
    for (int it = 0; it < 16; ++it){
        int idx = tid + it * 512;
        int j = idx & 127, kl = idx >> 7;
        int k = 128 + kl;
        sWa[j * 72 + kl] = (k < 136) ? f2bf(W1[k * 128 + j]) : 0;
        int k2 = idx >> 6, f = idx & 63;
        sWb[f * 136 + k2] = f2bf(W2[idx]);   // W2 [128][64] -> sWb[f][k]
    }
    __syncthreads();
    {   // c2: k = 128..159
        short8b a = *(const short8b*)(sZ + arow + 128);
        #pragma unroll
        for (int n = 0; n < 8; ++n){
            short8b b = *(const short8b*)(sWa + (n * 16 + l15) * 72 + kb * 8);
            acc[n] = __builtin_amdgcn_mfma_f32_16x16x32_bf16(a, b, acc[n], 0, 0, 0);
        }
    }
    // ---- BN + GELU epilogue (registers), then z1 -> sZ (stride 136) ----
    float scn[8], shn[8];
    #pragma unroll
    for (int n = 0; n < 8; ++n){
        int j = n * 16 + l15;
        float sc = bng[j] * rsqrtf(bnv[j] + BN_EPS);
        scn[n] = sc;
        shn[n] = bnb[j] - bnm[j] * sc + b1[j] * sc;  // fold b1 through BN: (a+b1)*sc+sh
    }
    __syncthreads();   // all waves done reading sZ
    #pragma unroll
    for (int n = 0; n < 8; ++n){
        #pragma unroll
        for (int r = 0; r < 4; ++r){
            float v = acc[n][r] * scn[n] + shn[n];
            float g = gelu_f(v);
            sZ[(w * 16 + kb * 4 + r) * 136 + n * 16 + l15] = f2bf(g);
        }
    }
    __syncthreads();

    // ---- layer2 MFMA: [128 q][128 k] @ [128 k][64 f] ----
    f32x4 acc2[4];
    #pragma unroll
    for (int n = 0; n < 4; ++n) acc2[n] = (f32x4){0.f, 0.f, 0.f, 0.f};
    const int arow2 = (w * 16 + l15) * 136 + kb * 8;
    #pragma unroll
    for (int s = 0; s < 4; ++s){
        int ks = s * 32;
        short8b a = *(const short8b*)(sZ + arow2 + ks);
        #pragma unroll
        for (int n = 0; n < 4; ++n){
            short8b b = *(const short8b*)(sWb + (n * 16 + l15) * 136 + ks + kb * 8);
            acc2[n] = __builtin_amdgcn_mfma_f32_16x16x32_bf16(a, b, acc2[n], 0, 0, 0);
        }
    }
    // ---- epilogue: +b2, gelu, dot W3, reduce, store ----
    float b3v = b3[0];
    f32x4 pvv = (f32x4){0.f, 0.f, 0.f, 0.f};
    #pragma unroll
    for (int n = 0; n < 4; ++n){
        int f = n * 16 + l15;
        float b2f = b2[f], w3f = W3[f];
        #pragma unroll
        for (int r = 0; r < 4; ++r)
            pvv[r] += gelu_f(acc2[n][r] + b2f) * w3f;
    }
    #pragma unroll
    for (int r = 0; r < 4; ++r){
        #pragma unroll
        for (int off = 1; off < 16; off <<= 1)
            pvv[r] += __shfl_xor(pvv[r], off, 64);
    }
    if (l15 == 0){
        #pragma unroll
        for (int r = 0; r < 4; ++r){
            int q = q0 + w * 16 + kb * 4 + r;
            if (q < N_QUERY) out[q] = pvv[r] + b3v;
        }
    }
}

extern "C" void kernel_launch(void* const* d_in, const int* in_sizes, int n_in,
                              void* d_out, int out_size, void* d_ws, size_t ws_size,
                              hipStream_t stream) {
    const float* x    = (const float*)d_in[0];
    const int*   ei   = (const int*)d_in[1];
    const float* ea   = (const float*)d_in[2];
    const int*   qe   = (const int*)d_in[3];
    const float* Wenc = (const float*)d_in[4];
    const float* benc = (const float*)d_in[5];
    const float* Wl   = (const float*)d_in[6];
    const float* bl   = (const float*)d_in[7];
    const float* Wr   = (const float*)d_in[8];
    const float* lng  = (const float*)d_in[9];
    const float* lnb  = (const float*)d_in[10];
    const float* W1   = (const float*)d_in[11];
    const float* b1   = (const float*)d_in[12];
    const float* bng  = (const float*)d_in[13];
    const float* bnb  = (const float*)d_in[14];
    const float* bnm  = (const float*)d_in[15];
    const float* bnv  = (const float*)d_in[16];
    const float* W2   = (const float*)d_in[17];
    const float* b2   = (const float*)d_in[18];
    const float* W3   = (const float*)d_in[19];
    const float* b3   = (const float*)d_in[20];
    float* out = (float*)d_out;

    char* ws = (char*)d_ws;
    const size_t NH = (size_t)N_NODES * H;
    float* hA  = (float*)ws;  ws += NH * 4;
    float* hB  = (float*)ws;  ws += NH * 4;
    int*   cnt = (int*)ws;    ws += (size_t)N_NODES * 4;
    int*   rsb = (int*)ws;    ws += ((size_t)N_NODES + 4) * 4;
    int*   cur = (int*)ws;    ws += (size_t)N_NODES * 4;
    int*   csr = (int*)ws;    ws += (size_t)N_EDGES * 4;
    int*   bsum= (int*)ws;    ws += 512 * 4;

    // CSR build
    k_zero_cnt<<<NBLK, 256, 0, stream>>>(cnt);
    k_count<<<(N_EDGES + 255) / 256, 256, 0, stream>>>(ei, cnt);
    k_scanA<<<NBLK, 256, 0, stream>>>(cnt, bsum);
    k_scanB<<<1, 512, 0, stream>>>(bsum);
    k_scanC<<<NBLK, 256, 0, stream>>>(cnt, bsum, rsb, cur);
    k_fill<<<(N_EDGES + 255) / 256, 256, 0, stream>>>(ei, cur, csr);

    // encoder
    k_enc<<<(N_NODES + 3) / 4, 256, 0, stream>>>(x, Wenc, benc, hA);

    // SAGE layers
    float* hc = hA; float* hn = hB;
    for (int l = 0; l < LAYERS; ++l){
        k_sage<<<512, 512, 0, stream>>>(hc, rsb, csr,
            Wl + (size_t)l * 2 * H * H, bl + l * H, Wr + (size_t)l * H * H,
            lng + l * H, lnb + l * H, hn);
        float* tmp = hc; hc = hn; hn = tmp;
    }

    // edge MLP (MFMA)
    int nbq = (N_QUERY + QB - 1) / QB;
    k_mlp_mfma<<<nbq, 512, 0, stream>>>(hc, qe, ea, W1, b1, bng, bnb, bnm, bnv, W2, b2, W3, b3, out);
}